// Round 1
// baseline (1715.898 us; speedup 1.0000x reference)
//
#include <hip/hip_runtime.h>
#include <stdint.h>
#include <math.h>

typedef unsigned long long u64;
typedef unsigned int u32;

#define CIN     1024
#define COUT    512
#define FH      50
#define FW      76
#define QP      80
#define HIDP    4096
#define FPITCH  4160            // 52*80
#define FPAD_FLOATS (CIN*FPITCH + 512)
#define NPOS    3800
#define NA      34200
#define PRE_N   4000
#define POST_N  2000
#define MASKW   63
#define TBN     4032

// ---------------- async global->LDS (4B granule: per-lane src, lds base + lane*4)
__device__ __forceinline__ void async_copy4(const float* g, float* l) {
  __builtin_amdgcn_global_load_lds(
      (__attribute__((address_space(1))) void*)(g),
      (__attribute__((address_space(3))) void*)(l),
      4, 0, 0);
}

// ---------------- K1a: build zero-padded feats [1024][52*80]
__global__ void k_pad(const float* __restrict__ feats, float* __restrict__ fpad) {
  int idx = blockIdx.x * 256 + threadIdx.x;   // grid covers FPAD_FLOATS exactly
  float v = 0.f;
  if (idx < CIN * FPITCH) {
    int c = idx / FPITCH;
    int rq = idx - c * FPITCH;
    int r = rq / QP;
    int u = rq - r * QP;
    if (r >= 1 && r <= FH && u >= 1 && u <= FW)
      v = feats[c * (FH * FW) + (r - 1) * FW + (u - 1)];
  }
  fpad[idx] = v;
}

// ---------------- K1b: weight transpose w[oc][k] -> wt[k][oc], k = c*9+tap
__global__ void k_wt(const float* __restrict__ w, float* __restrict__ wt) {
  __shared__ float t[64][65];
  int k0 = blockIdx.x * 64, oc0 = blockIdx.y * 64;
  int tx = threadIdx.x & 63, tg = threadIdx.x >> 6;
#pragma unroll
  for (int rr = 0; rr < 16; rr++) {
    int row = tg * 16 + rr;
    t[row][tx] = w[(size_t)(oc0 + row) * 9216 + k0 + tx];
  }
  __syncthreads();
#pragma unroll
  for (int rr = 0; rr < 16; rr++) {
    int kr = tg * 16 + rr;
    wt[(size_t)(k0 + kr) * 512 + oc0 + tx] = t[tx][kr];
  }
}

// ---------------- init control structures
__global__ void k_init(u32* __restrict__ hist, u32* __restrict__ ctrl,
                       double4* __restrict__ tb, float* __restrict__ ts) {
  int i = blockIdx.x * 256 + threadIdx.x;   // grid = 65536 exactly
  hist[i] = 0;
  if (i < 8) ctrl[i] = 0;
  if (i >= PRE_N && i < TBN) { tb[i] = make_double4(0.0, 0.0, 0.0, 0.0); ts[i] = -1.0e9f; }
}

// ---------------- K2: conv3x3 + bias + relu (implicit GEMM, fp32 FMA + chunked fp64 accum)
__device__ __forceinline__ void stage_chunk(const float* __restrict__ fpad,
                                            float (*Bl)[256],
                                            int cc, int q0, int wv, int lane) {
#pragma unroll
  for (int rr = 0; rr < 5; rr++) {
    int r = wv * 5 + rr;           // 18 rows total; wave 3 does only 3
    if (r < 18) {
      int ci = r / 9, tap = r - ci * 9;
      int s = (tap / 3) * QP + (tap % 3);
      const float* src = fpad + (size_t)(cc * 2 + ci) * FPITCH + q0 + s;
#pragma unroll
      for (int part = 0; part < 4; part++)
        async_copy4(src + part * 64 + lane, &Bl[r][part * 64]);
    }
  }
}

__device__ __forceinline__ void compute_chunk(const float (*Bl)[256],
                                              const float* __restrict__ wt,
                                              int cc, int ocb, int lane,
                                              float acc[8][4]) {
#pragma unroll
  for (int ks = 0; ks < 18; ks++) {
    float4 b4 = *(const float4*)&Bl[ks][lane * 4];
    const float* wp = wt + (((size_t)cc * 18 + ks) << 9) + ocb;  // uniform -> s_load
#pragma unroll
    for (int i = 0; i < 8; i++) {
      float w = wp[i];
      acc[i][0] = fmaf(w, b4.x, acc[i][0]);
      acc[i][1] = fmaf(w, b4.y, acc[i][1]);
      acc[i][2] = fmaf(w, b4.z, acc[i][2]);
      acc[i][3] = fmaf(w, b4.w, acc[i][3]);
    }
  }
}

__global__ __launch_bounds__(256, 1) void k_conv(const float* __restrict__ fpad,
                                                 const float* __restrict__ wt,
                                                 const float* __restrict__ bconv,
                                                 float* __restrict__ hid) {
  __shared__ __align__(16) float Bl[2][18][256];     // 36 KiB, double-buffered
  const int tid = threadIdx.x;
  const int lane = tid & 63;
  const int wv = __builtin_amdgcn_readfirstlane(tid >> 6);
  const int q0 = blockIdx.x << 8;                    // 16 q-tiles of 256
  const int ocb = (blockIdx.y << 5) + (wv << 3);     // 16 oc-tiles of 32; 8 oc per wave

  double acc64[8][4];
  float acc32[8][4];
#pragma unroll
  for (int i = 0; i < 8; i++)
#pragma unroll
    for (int j = 0; j < 4; j++) { acc64[i][j] = 0.0; acc32[i][j] = 0.f; }

  stage_chunk(fpad, Bl[0], 0, q0, wv, lane);

#pragma unroll 1
  for (int cc = 0; cc < 512; cc += 2) {
    __syncthreads();                                  // stage(cc) complete
    if (cc + 1 < 512) stage_chunk(fpad, Bl[1], cc + 1, q0, wv, lane);
    compute_chunk(Bl[0], wt, cc, ocb, lane, acc32);
    __syncthreads();                                  // stage(cc+1) complete
    if (cc + 2 < 512) stage_chunk(fpad, Bl[0], cc + 2, q0, wv, lane);
    compute_chunk(Bl[1], wt, cc + 1, ocb, lane, acc32);
    if ((cc & 2) == 2) {                              // fold every 4 chunks (72 k-steps)
#pragma unroll
      for (int i = 0; i < 8; i++)
#pragma unroll
        for (int j = 0; j < 4; j++) { acc64[i][j] += (double)acc32[i][j]; acc32[i][j] = 0.f; }
    }
  }

#pragma unroll
  for (int i = 0; i < 8; i++) {
    double bias = (double)bconv[ocb + i];
    float4 o;
    double v0 = acc64[i][0] + bias; o.x = v0 > 0.0 ? (float)v0 : 0.f;
    double v1 = acc64[i][1] + bias; o.y = v1 > 0.0 ? (float)v1 : 0.f;
    double v2 = acc64[i][2] + bias; o.z = v2 > 0.0 ? (float)v2 : 0.f;
    double v3 = acc64[i][3] + bias; o.w = v3 > 0.0 ? (float)v3 : 0.f;
    *(float4*)&hid[((size_t)(ocb + i) << 12) + q0 + (lane << 2)] = o;
  }
}

// ---------------- K3: 1x1 convs (9 score channels [A:], 36 delta channels), fp64 accum
__global__ void k_head(const float* __restrict__ hid,
                       const float* __restrict__ wcls, const float* __restrict__ bcls,
                       const float* __restrict__ wreg, const float* __restrict__ breg,
                       float* __restrict__ scoresb, float* __restrict__ deltab) {
  int o = blockIdx.y;                      // 0..44
  int pos = blockIdx.x * 256 + threadIdx.x;
  if (pos >= NPOS) return;
  int y = pos / FW, x = pos - y * FW;
  int q = y * QP + x;
  const float* wp; float bias;
  if (o < 9) { wp = wcls + (size_t)(9 + o) * 512; bias = bcls[9 + o]; }
  else       { wp = wreg + (size_t)(o - 9) * 512; bias = breg[o - 9]; }
  double acc = 0.0;
#pragma unroll 8
  for (int c = 0; c < 512; c++)
    acc += (double)hid[((size_t)c << 12) + q] * (double)wp[c];
  float r = (float)(acc + (double)bias);
  if (o < 9) scoresb[o * NPOS + pos] = r;
  else       deltab[(o - 9) * NPOS + pos] = r;
}

// ---------------- K4: proposals (fp64), masked scores, sort keys, 16-bit histogram
__device__ __constant__ float AW[9] = {184.f, 368.f, 736.f, 128.f, 256.f, 512.f, 88.f, 176.f, 352.f};
__device__ __constant__ float AH[9] = {96.f, 192.f, 384.f, 128.f, 256.f, 512.f, 176.f, 352.f, 704.f};

__global__ void k_prop(const float* __restrict__ scoresb, const float* __restrict__ deltab,
                       double4* __restrict__ boxesd, u64* __restrict__ keys,
                       float* __restrict__ smask, u32* __restrict__ hist,
                       float* __restrict__ dout) {
  int g = blockIdx.x * 256 + threadIdx.x;
  if (g < 10000) dout[g] = 0.f;            // zero the harness-poisoned output
  if (g >= NA) return;
  int pos = g / 9, a = g - pos * 9;
  int y = pos / FW, x = pos - y * FW;
  double w = (double)AW[a], h = (double)AH[a];
  double cx = x * 16.0 + 8.0, cy = y * 16.0 + 8.0;   // exact: xc+0.5
  double d0 = (double)deltab[(4 * a + 0) * NPOS + pos];
  double d1 = (double)deltab[(4 * a + 1) * NPOS + pos];
  double d2 = (double)deltab[(4 * a + 2) * NPOS + pos];
  double d3 = (double)deltab[(4 * a + 3) * NPOS + pos];
  double pcx = d0 * w + cx, pcy = d1 * h + cy;
  double pw = exp(d2) * w, ph = exp(d3) * h;
  double px1 = fmin(fmax(pcx - 0.5 * pw, 0.0), 1215.0);
  double py1 = fmin(fmax(pcy - 0.5 * ph, 0.0), 799.0);
  double px2 = fmin(fmax(pcx + 0.5 * pw, 0.0), 1215.0);
  double py2 = fmin(fmax(pcy + 0.5 * ph, 0.0), 799.0);
  bool valid = (px2 - px1 + 1.0 >= 16.0) && (py2 - py1 + 1.0 >= 16.0);
  float sc = scoresb[a * NPOS + pos];
  float ms = valid ? sc : -1.0e9f;
  boxesd[g] = make_double4(px1, py1, px2, py2);
  smask[g] = ms;
  u32 u = __float_as_uint(ms);
  u = (u >> 31) ? ~u : (u | 0x80000000u);            // monotone float->uint
  keys[g] = ((u64)u << 32) | (u32)(~(u32)g);         // score desc, index asc
  atomicAdd(&hist[u >> 16], 1u);
}

// ---------------- K5: find histogram cutoff bin for top-4000
__global__ void k_scan(const u32* __restrict__ hist, u32* __restrict__ ctrl) {
  __shared__ u32 cs[256];
  __shared__ u32 sfx[256];
  int t = threadIdx.x;
  u32 s = 0;
  for (int i = 0; i < 256; i++) s += hist[t * 256 + i];
  cs[t] = s;
  __syncthreads();
  if (t == 0) {
    u32 c = 0;
    for (int i = 255; i >= 0; i--) { sfx[i] = c; c += cs[i]; }
  }
  __syncthreads();
  u32 before = sfx[t];
  u32 c = 0;
  for (int b = 255; b >= 0; b--) {
    u32 hv = hist[t * 256 + b];
    if (before + c < PRE_N && before + c + hv >= PRE_N) {
      ctrl[0] = (u32)(t * 256 + b);   // cutoff bin B
      ctrl[1] = before + c;           // count strictly above B
    }
    c += hv;
  }
}

// ---------------- K6: compact candidates (bin >= B)
__global__ void k_compact(const u64* __restrict__ keys, u32* __restrict__ ctrl,
                          u64* __restrict__ candK, u32* __restrict__ candG) {
  int g = blockIdx.x * 256 + threadIdx.x;
  if (g >= NA) return;
  u32 binB = ctrl[0];
  u64 k = keys[g];
  if ((u32)(k >> 48) >= binB) {
    u32 idx = atomicAdd(&ctrl[2], 1u);
    candK[idx] = k;
    candG[idx] = g;
  }
}

// ---------------- K7: exact rank by counting; scatter top-4000 in sorted order
__global__ void k_rank(const u64* __restrict__ candK, const u32* __restrict__ candG,
                       const u32* __restrict__ ctrl, const double4* __restrict__ boxesd,
                       const float* __restrict__ smask, double4* __restrict__ tb,
                       float* __restrict__ ts) {
  __shared__ u64 kk[256];
  u32 m = ctrl[2];
  int i = blockIdx.x * 256 + threadIdx.x;
  u64 my = (i < (int)m) ? candK[i] : 0ULL;
  u32 rank = 0;
  for (u32 base = 0; base < m; base += 256) {
    u32 j = base + threadIdx.x;
    kk[threadIdx.x] = (j < m) ? candK[j] : 0ULL;
    __syncthreads();
    u32 lim = m - base; if (lim > 256) lim = 256;
    for (u32 tt = 0; tt < lim; tt++) rank += (kk[tt] > my) ? 1u : 0u;
    __syncthreads();
  }
  if (i < (int)m && rank < PRE_N) {
    u32 g = candG[i];
    tb[rank] = boxesd[g];
    ts[rank] = smask[g];
  }
}

// ---------------- K8: NMS suppression bitmask (fp64 IoU, multiply form)
__global__ void k_mask(const double4* __restrict__ tb, u64* __restrict__ mask) {
  __shared__ double4 bx[64];
  int w = blockIdx.x;                         // 0..62
  int i = blockIdx.y * 256 + threadIdx.x;
  if (threadIdx.x < 64) bx[threadIdx.x] = tb[w * 64 + threadIdx.x];
  __syncthreads();
  if (i >= PRE_N) return;
  double4 b = tb[i];
  double ai = (b.z - b.x + 1.0) * (b.w - b.y + 1.0);
  u64 word = 0;
#pragma unroll 8
  for (int j = 0; j < 64; j++) {
    int jg = w * 64 + j;
    double4 cc = bx[j];
    double xx1 = fmax(b.x, cc.x), yy1 = fmax(b.y, cc.y);
    double xx2 = fmin(b.z, cc.z), yy2 = fmin(b.w, cc.w);
    double iw = xx2 - xx1 + 1.0, ih = yy2 - yy1 + 1.0;
    iw = iw > 0.0 ? iw : 0.0; ih = ih > 0.0 ? ih : 0.0;
    double inter = iw * ih;
    double aj = (cc.z - cc.x + 1.0) * (cc.w - cc.y + 1.0);
    bool sup = (jg > i) && (inter > 0.7 * (ai + aj - inter));
    word |= sup ? (1ULL << j) : 0ULL;
  }
  mask[(size_t)i * MASKW + w] = word;
}

// ---------------- K9: sequential greedy scan (1 wave) + compact first 2000 to out
__global__ __launch_bounds__(64, 1) void k_nms(const u64* __restrict__ mask,
                                               const float* __restrict__ ts,
                                               const double4* __restrict__ tb,
                                               float* __restrict__ out) {
  int lane = threadIdx.x;
  u64 keep = 0;                                 // lane t owns keep word t (t<63)
  for (int w = 0; w < MASKW; w++) {
    float s = ts[w * 64 + lane];
    u64 b = __ballot(s > -5.0e8f);
    if (lane == w) keep = b;
  }
  for (int c = 0; c < MASKW; c++) {
    u64 cur = __shfl(keep, c);
    u64 D = mask[(size_t)(c * 64 + lane) * MASKW + c];    // diagonal word
    for (int j = 0; j < 64; j++) {
      u64 Dj = __shfl(D, j);
      if ((cur >> j) & 1ULL) cur &= ~Dj;                  // uniform
    }
    if (lane == c) keep = cur;
    // suppress later words from this chunk's kept rows (batched loads)
    u64 supp = 0;
#pragma unroll 1
    for (int jb = 0; jb < 64; jb += 16) {
      u64 v[16];
#pragma unroll
      for (int u2 = 0; u2 < 16; u2++)
        v[u2] = (lane < MASKW) ? mask[(size_t)(c * 64 + jb + u2) * MASKW + lane] : 0ULL;
#pragma unroll
      for (int u2 = 0; u2 < 16; u2++)
        if ((cur >> (jb + u2)) & 1ULL) supp |= v[u2];
    }
    keep &= ~supp;
  }
  // rank kept boxes, write first 2000 (+scores at out+8000)
  int pc = __popcll(keep);
  int pre = pc;
#pragma unroll
  for (int off = 1; off < 64; off <<= 1) {
    int v = __shfl_up(pre, off);
    if (lane >= off) pre += v;
  }
  pre -= pc;   // exclusive prefix
#pragma unroll 1
  for (int j = 0; j < 64; j++) {
    if ((keep >> j) & 1ULL) {
      int r = pre + __popcll(keep & ((1ULL << j) - 1ULL));
      if (r < POST_N) {
        int i = lane * 64 + j;
        double4 b = tb[i];
        out[r * 4 + 0] = (float)b.x;
        out[r * 4 + 1] = (float)b.y;
        out[r * 4 + 2] = (float)b.z;
        out[r * 4 + 3] = (float)b.w;
        out[8000 + r] = ts[i];
      }
    }
  }
}

// =====================================================================
extern "C" void kernel_launch(void* const* d_in, const int* in_sizes, int n_in,
                              void* d_out, int out_size, void* d_ws, size_t ws_size,
                              hipStream_t stream) {
  const float* feats  = (const float*)d_in[1];
  const float* w_conv = (const float*)d_in[2];
  const float* b_conv = (const float*)d_in[3];
  const float* w_cls  = (const float*)d_in[4];
  const float* b_cls  = (const float*)d_in[5];
  const float* w_reg  = (const float*)d_in[6];
  const float* b_reg  = (const float*)d_in[7];
  float* out = (float*)d_out;

  char* p = (char*)d_ws;
  auto carve = [&p](size_t bytes) -> void* {
    void* r = (void*)p;
    p += (bytes + 255) & ~(size_t)255;
    return r;
  };
  float*   fpad    = (float*)carve(sizeof(float) * FPAD_FLOATS);       // 17.0 MB
  float*   wt      = (float*)carve(sizeof(float) * 9216 * 512);        // 18.9 MB
  float*   hid     = (float*)carve(sizeof(float) * COUT * HIDP);       //  8.4 MB
  float*   scoresb = (float*)carve(sizeof(float) * 9 * NPOS);
  float*   deltab  = (float*)carve(sizeof(float) * 36 * NPOS);
  double4* boxesd  = (double4*)carve(sizeof(double4) * NA);
  u64*     keys    = (u64*)carve(sizeof(u64) * NA);
  float*   smask   = (float*)carve(sizeof(float) * NA);
  u32*     hist    = (u32*)carve(sizeof(u32) * 65536);
  u32*     ctrl    = (u32*)carve(256);
  u64*     candK   = (u64*)carve(sizeof(u64) * NA);
  u32*     candG   = (u32*)carve(sizeof(u32) * NA);
  double4* tb      = (double4*)carve(sizeof(double4) * TBN);
  float*   ts      = (float*)carve(sizeof(float) * TBN);
  u64*     maskb   = (u64*)carve(sizeof(u64) * (size_t)TBN * MASKW);   //  2.0 MB
  (void)ws_size; (void)in_sizes; (void)n_in; (void)out_size;           // ~47 MB total

  k_pad<<<16642, 256, 0, stream>>>(feats, fpad);
  k_wt<<<dim3(144, 8), 256, 0, stream>>>(w_conv, wt);
  k_init<<<256, 256, 0, stream>>>(hist, ctrl, tb, ts);
  k_conv<<<dim3(16, 16), 256, 0, stream>>>(fpad, wt, b_conv, hid);
  k_head<<<dim3(15, 45), 256, 0, stream>>>(hid, w_cls, b_cls, w_reg, b_reg, scoresb, deltab);
  k_prop<<<134, 256, 0, stream>>>(scoresb, deltab, boxesd, keys, smask, hist, out);
  k_scan<<<1, 256, 0, stream>>>(hist, ctrl);
  k_compact<<<134, 256, 0, stream>>>(keys, ctrl, candK, candG);
  k_rank<<<134, 256, 0, stream>>>(candK, candG, ctrl, boxesd, smask, tb, ts);
  k_mask<<<dim3(MASKW, 16), 256, 0, stream>>>(tb, maskb);
  k_nms<<<1, 64, 0, stream>>>(maskb, ts, tb, out);
}

// Round 2
// 1204.146 us; speedup vs baseline: 1.4250x; 1.4250x over previous
//
#include <hip/hip_runtime.h>
#include <stdint.h>
#include <math.h>

typedef unsigned long long u64;
typedef unsigned int u32;

#define CIN     1024
#define COUT    512
#define FH      50
#define FW      76
#define QP      80
#define HIDP    4096
#define FPITCH  4160            // 52*80
#define FPAD_FLOATS (CIN*FPITCH + 512)
#define NPOS    3800
#define NA      34200
#define PRE_N   4000
#define POST_N  2000
#define MASKW   63
#define TBN     4032
#define KSLICES 4
#define CHUNKS_PER_SLICE 128    // 512 chunks (of 2 cin) / 4 slices

// ---------------- async global->LDS (4B granule: per-lane src, lds base + lane*4)
__device__ __forceinline__ void async_copy4(const float* g, float* l) {
  __builtin_amdgcn_global_load_lds(
      (__attribute__((address_space(1))) void*)(g),
      (__attribute__((address_space(3))) void*)(l),
      4, 0, 0);
}

// ---------------- K1a: build zero-padded feats [1024][52*80]
__global__ void k_pad(const float* __restrict__ feats, float* __restrict__ fpad) {
  int idx = blockIdx.x * 256 + threadIdx.x;
  float v = 0.f;
  if (idx < CIN * FPITCH) {
    int c = idx / FPITCH;
    int rq = idx - c * FPITCH;
    int r = rq / QP;
    int u = rq - r * QP;
    if (r >= 1 && r <= FH && u >= 1 && u <= FW)
      v = feats[c * (FH * FW) + (r - 1) * FW + (u - 1)];
  }
  fpad[idx] = v;
}

// ---------------- K1b: weight transpose w[oc][k] -> wt[k][oc], k = c*9+tap
__global__ void k_wt(const float* __restrict__ w, float* __restrict__ wt) {
  __shared__ float t[64][65];
  int k0 = blockIdx.x * 64, oc0 = blockIdx.y * 64;
  int tx = threadIdx.x & 63, tg = threadIdx.x >> 6;
#pragma unroll
  for (int rr = 0; rr < 16; rr++) {
    int row = tg * 16 + rr;
    t[row][tx] = w[(size_t)(oc0 + row) * 9216 + k0 + tx];
  }
  __syncthreads();
#pragma unroll
  for (int rr = 0; rr < 16; rr++) {
    int kr = tg * 16 + rr;
    wt[(size_t)(k0 + kr) * 512 + oc0 + tx] = t[tx][kr];
  }
}

// ---------------- init control structures
__global__ void k_init(u32* __restrict__ hist, u32* __restrict__ ctrl,
                       double4* __restrict__ tb, float* __restrict__ ts) {
  int i = blockIdx.x * 256 + threadIdx.x;   // grid = 65536 exactly
  hist[i] = 0;
  if (i < 8) ctrl[i] = 0;
  if (i >= PRE_N && i < TBN) { tb[i] = make_double4(0.0, 0.0, 0.0, 0.0); ts[i] = -1.0e9f; }
}

// ---------------- K2: conv3x3 split-K implicit GEMM (fp32 FMA + chunked fp64 accum)
__device__ __forceinline__ void stage_chunk(const float* __restrict__ fpad,
                                            float (*Bl)[256],
                                            int cc, int q0, int wv, int lane) {
#pragma unroll
  for (int rr = 0; rr < 5; rr++) {
    int r = wv * 5 + rr;           // 18 rows total; wave 3 does only 3
    if (r < 18) {
      int ci = r / 9, tap = r - ci * 9;
      int s = (tap / 3) * QP + (tap % 3);
      const float* src = fpad + (size_t)(cc * 2 + ci) * FPITCH + q0 + s;
#pragma unroll
      for (int part = 0; part < 4; part++)
        async_copy4(src + part * 64 + lane, &Bl[r][part * 64]);
    }
  }
}

__device__ __forceinline__ void compute_chunk(const float (*Bl)[256],
                                              const float* __restrict__ wt,
                                              int cc, int ocb, int lane,
                                              float acc[8][4]) {
#pragma unroll
  for (int ks = 0; ks < 18; ks++) {
    float4 b4 = *(const float4*)&Bl[ks][lane * 4];
    const float* wp = wt + (((size_t)cc * 18 + ks) << 9) + ocb;  // uniform -> s_load
#pragma unroll
    for (int i = 0; i < 8; i++) {
      float w = wp[i];
      acc[i][0] = fmaf(w, b4.x, acc[i][0]);
      acc[i][1] = fmaf(w, b4.y, acc[i][1]);
      acc[i][2] = fmaf(w, b4.z, acc[i][2]);
      acc[i][3] = fmaf(w, b4.w, acc[i][3]);
    }
  }
}

__global__ __launch_bounds__(256, 4) void k_conv(const float* __restrict__ fpad,
                                                 const float* __restrict__ wt,
                                                 float* __restrict__ hidp) {
  __shared__ __align__(16) float Bl[2][18][256];     // 36 KiB, double-buffered
  const int tid = threadIdx.x;
  const int lane = tid & 63;
  const int wv = __builtin_amdgcn_readfirstlane(tid >> 6);
  const int q0 = blockIdx.x << 8;                    // 16 q-tiles of 256
  const int ocb = (blockIdx.y << 5) + (wv << 3);     // 16 oc-tiles of 32; 8 oc per wave
  const int c0 = blockIdx.z * CHUNKS_PER_SLICE;      // K-slice base chunk

  double acc64[8][4];
  float acc32[8][4];
#pragma unroll
  for (int i = 0; i < 8; i++)
#pragma unroll
    for (int j = 0; j < 4; j++) { acc64[i][j] = 0.0; acc32[i][j] = 0.f; }

  stage_chunk(fpad, Bl[0], c0, q0, wv, lane);

#pragma unroll 1
  for (int cc = 0; cc < CHUNKS_PER_SLICE; cc += 2) {
    __syncthreads();                                  // stage(cc) complete
    stage_chunk(fpad, Bl[1], c0 + cc + 1, q0, wv, lane);
    compute_chunk(Bl[0], wt, c0 + cc, ocb, lane, acc32);
    __syncthreads();                                  // stage(cc+1) complete
    if (cc + 2 < CHUNKS_PER_SLICE) stage_chunk(fpad, Bl[0], c0 + cc + 2, q0, wv, lane);
    compute_chunk(Bl[1], wt, c0 + cc + 1, ocb, lane, acc32);
    if ((cc & 2) == 2) {                              // fold every 4 chunks (72 k-steps)
#pragma unroll
      for (int i = 0; i < 8; i++)
#pragma unroll
        for (int j = 0; j < 4; j++) { acc64[i][j] += (double)acc32[i][j]; acc32[i][j] = 0.f; }
    }
  }

  // fp32 partials per slice (rounding ~4e-9 << fp32 fold noise ~1e-7 << sort gaps ~1e-6)
#pragma unroll
  for (int i = 0; i < 8; i++) {
    float4 o;
    o.x = (float)acc64[i][0];
    o.y = (float)acc64[i][1];
    o.z = (float)acc64[i][2];
    o.w = (float)acc64[i][3];
    *(float4*)&hidp[((size_t)(blockIdx.z * COUT + ocb + i) << 12) + q0 + (lane << 2)] = o;
  }
}

// ---------------- K2b: reduce 4 K-slice partials + bias + relu
__global__ void k_reduce(const float* __restrict__ hidp, const float* __restrict__ bconv,
                         float* __restrict__ hid) {
  int idx = blockIdx.x * 256 + threadIdx.x;          // 2,097,152 total
  int oc = idx >> 12;
  double s = (double)hidp[idx];
  s += (double)hidp[idx + (1 << 21)];
  s += (double)hidp[idx + (2 << 21)];
  s += (double)hidp[idx + (3 << 21)];
  s += (double)bconv[oc];
  hid[idx] = s > 0.0 ? (float)s : 0.f;
}

// ---------------- K3: 1x1 convs (9 score channels [A:], 36 delta channels), fp64 accum
__global__ void k_head(const float* __restrict__ hid,
                       const float* __restrict__ wcls, const float* __restrict__ bcls,
                       const float* __restrict__ wreg, const float* __restrict__ breg,
                       float* __restrict__ scoresb, float* __restrict__ deltab) {
  int o = blockIdx.y;                      // 0..44
  int pos = blockIdx.x * 256 + threadIdx.x;
  if (pos >= NPOS) return;
  int y = pos / FW, x = pos - y * FW;
  int q = y * QP + x;
  const float* wp; float bias;
  if (o < 9) { wp = wcls + (size_t)(9 + o) * 512; bias = bcls[9 + o]; }
  else       { wp = wreg + (size_t)(o - 9) * 512; bias = breg[o - 9]; }
  double acc = 0.0;
#pragma unroll 8
  for (int c = 0; c < 512; c++)
    acc += (double)hid[((size_t)c << 12) + q] * (double)wp[c];
  float r = (float)(acc + (double)bias);
  if (o < 9) scoresb[o * NPOS + pos] = r;
  else       deltab[(o - 9) * NPOS + pos] = r;
}

// ---------------- K4: proposals (fp64), masked scores, sort keys, 16-bit histogram
__device__ __constant__ float AW[9] = {184.f, 368.f, 736.f, 128.f, 256.f, 512.f, 88.f, 176.f, 352.f};
__device__ __constant__ float AH[9] = {96.f, 192.f, 384.f, 128.f, 256.f, 512.f, 176.f, 352.f, 704.f};

__global__ void k_prop(const float* __restrict__ scoresb, const float* __restrict__ deltab,
                       double4* __restrict__ boxesd, u64* __restrict__ keys,
                       float* __restrict__ smask, u32* __restrict__ hist,
                       float* __restrict__ dout) {
  int g = blockIdx.x * 256 + threadIdx.x;
  if (g < 10000) dout[g] = 0.f;            // zero the harness-poisoned output
  if (g >= NA) return;
  int pos = g / 9, a = g - pos * 9;
  int y = pos / FW, x = pos - y * FW;
  double w = (double)AW[a], h = (double)AH[a];
  double cx = x * 16.0 + 8.0, cy = y * 16.0 + 8.0;   // exact: xc+0.5
  double d0 = (double)deltab[(4 * a + 0) * NPOS + pos];
  double d1 = (double)deltab[(4 * a + 1) * NPOS + pos];
  double d2 = (double)deltab[(4 * a + 2) * NPOS + pos];
  double d3 = (double)deltab[(4 * a + 3) * NPOS + pos];
  double pcx = d0 * w + cx, pcy = d1 * h + cy;
  double pw = exp(d2) * w, ph = exp(d3) * h;
  double px1 = fmin(fmax(pcx - 0.5 * pw, 0.0), 1215.0);
  double py1 = fmin(fmax(pcy - 0.5 * ph, 0.0), 799.0);
  double px2 = fmin(fmax(pcx + 0.5 * pw, 0.0), 1215.0);
  double py2 = fmin(fmax(pcy + 0.5 * ph, 0.0), 799.0);
  bool valid = (px2 - px1 + 1.0 >= 16.0) && (py2 - py1 + 1.0 >= 16.0);
  float sc = scoresb[a * NPOS + pos];
  float ms = valid ? sc : -1.0e9f;
  boxesd[g] = make_double4(px1, py1, px2, py2);
  smask[g] = ms;
  u32 u = __float_as_uint(ms);
  u = (u >> 31) ? ~u : (u | 0x80000000u);            // monotone float->uint
  keys[g] = ((u64)u << 32) | (u32)(~(u32)g);         // score desc, index asc
  atomicAdd(&hist[u >> 16], 1u);
}

// ---------------- K5: find histogram cutoff bin for top-4000
__global__ void k_scan(const u32* __restrict__ hist, u32* __restrict__ ctrl) {
  __shared__ u32 cs[256];
  __shared__ u32 sfx[256];
  int t = threadIdx.x;
  u32 s = 0;
  for (int i = 0; i < 256; i++) s += hist[t * 256 + i];
  cs[t] = s;
  __syncthreads();
  if (t == 0) {
    u32 c = 0;
    for (int i = 255; i >= 0; i--) { sfx[i] = c; c += cs[i]; }
  }
  __syncthreads();
  u32 before = sfx[t];
  u32 c = 0;
  for (int b = 255; b >= 0; b--) {
    u32 hv = hist[t * 256 + b];
    if (before + c < PRE_N && before + c + hv >= PRE_N) {
      ctrl[0] = (u32)(t * 256 + b);   // cutoff bin B
      ctrl[1] = before + c;           // count strictly above B
    }
    c += hv;
  }
}

// ---------------- K6: compact candidates (bin >= B)
__global__ void k_compact(const u64* __restrict__ keys, u32* __restrict__ ctrl,
                          u64* __restrict__ candK, u32* __restrict__ candG) {
  int g = blockIdx.x * 256 + threadIdx.x;
  if (g >= NA) return;
  u32 binB = ctrl[0];
  u64 k = keys[g];
  if ((u32)(k >> 48) >= binB) {
    u32 idx = atomicAdd(&ctrl[2], 1u);
    candK[idx] = k;
    candG[idx] = g;
  }
}

// ---------------- K7: exact rank by counting; scatter top-4000 in sorted order
__global__ void k_rank(const u64* __restrict__ candK, const u32* __restrict__ candG,
                       const u32* __restrict__ ctrl, const double4* __restrict__ boxesd,
                       const float* __restrict__ smask, double4* __restrict__ tb,
                       float* __restrict__ ts) {
  __shared__ u64 kk[256];
  u32 m = ctrl[2];
  if (blockIdx.x * 256 >= m) return;        // prune empty blocks
  int i = blockIdx.x * 256 + threadIdx.x;
  u64 my = (i < (int)m) ? candK[i] : 0ULL;
  u32 rank = 0;
  for (u32 base = 0; base < m; base += 256) {
    u32 j = base + threadIdx.x;
    kk[threadIdx.x] = (j < m) ? candK[j] : 0ULL;
    __syncthreads();
    u32 lim = m - base; if (lim > 256) lim = 256;
    for (u32 tt = 0; tt < lim; tt++) rank += (kk[tt] > my) ? 1u : 0u;
    __syncthreads();
  }
  if (i < (int)m && rank < PRE_N) {
    u32 g = candG[i];
    tb[rank] = boxesd[g];
    ts[rank] = smask[g];
  }
}

// ---------------- K8: NMS suppression bitmask (fp64 IoU, multiply form)
__global__ void k_mask(const double4* __restrict__ tb, u64* __restrict__ mask) {
  __shared__ double4 bx[64];
  int w = blockIdx.x;                         // 0..62
  int i = blockIdx.y * 256 + threadIdx.x;
  if (threadIdx.x < 64) bx[threadIdx.x] = tb[w * 64 + threadIdx.x];
  __syncthreads();
  if (i >= PRE_N) return;
  double4 b = tb[i];
  double ai = (b.z - b.x + 1.0) * (b.w - b.y + 1.0);
  u64 word = 0;
#pragma unroll 8
  for (int j = 0; j < 64; j++) {
    int jg = w * 64 + j;
    double4 cc = bx[j];
    double xx1 = fmax(b.x, cc.x), yy1 = fmax(b.y, cc.y);
    double xx2 = fmin(b.z, cc.z), yy2 = fmin(b.w, cc.w);
    double iw = xx2 - xx1 + 1.0, ih = yy2 - yy1 + 1.0;
    iw = iw > 0.0 ? iw : 0.0; ih = ih > 0.0 ? ih : 0.0;
    double inter = iw * ih;
    double aj = (cc.z - cc.x + 1.0) * (cc.w - cc.y + 1.0);
    bool sup = (jg > i) && (inter > 0.7 * (ai + aj - inter));
    word |= sup ? (1ULL << j) : 0ULL;
  }
  mask[(size_t)i * MASKW + w] = word;
}

// ---------------- K9: sequential greedy scan (1 wave) + compact first 2000 to out
__global__ __launch_bounds__(64, 1) void k_nms(const u64* __restrict__ mask,
                                               const float* __restrict__ ts,
                                               const double4* __restrict__ tb,
                                               float* __restrict__ out) {
  int lane = threadIdx.x;
  u64 keep = 0;                                 // lane t owns keep word t (t<63)
  for (int w = 0; w < MASKW; w++) {
    float s = ts[w * 64 + lane];
    u64 b = __ballot(s > -5.0e8f);
    if (lane == w) keep = b;
  }
  for (int c = 0; c < MASKW; c++) {
    u64 cur = __shfl(keep, c);
    u64 D = mask[(size_t)(c * 64 + lane) * MASKW + c];    // diagonal word
    for (int j = 0; j < 64; j++) {
      u64 Dj = __shfl(D, j);
      if ((cur >> j) & 1ULL) cur &= ~Dj;                  // uniform
    }
    if (lane == c) keep = cur;
    // suppress later words from this chunk's kept rows (batched loads)
    u64 supp = 0;
#pragma unroll 1
    for (int jb = 0; jb < 64; jb += 16) {
      u64 v[16];
#pragma unroll
      for (int u2 = 0; u2 < 16; u2++)
        v[u2] = (lane < MASKW) ? mask[(size_t)(c * 64 + jb + u2) * MASKW + lane] : 0ULL;
#pragma unroll
      for (int u2 = 0; u2 < 16; u2++)
        if ((cur >> (jb + u2)) & 1ULL) supp |= v[u2];
    }
    keep &= ~supp;
  }
  // rank kept boxes, write first 2000 (+scores at out+8000)
  int pc = __popcll(keep);
  int pre = pc;
#pragma unroll
  for (int off = 1; off < 64; off <<= 1) {
    int v = __shfl_up(pre, off);
    if (lane >= off) pre += v;
  }
  pre -= pc;   // exclusive prefix
#pragma unroll 1
  for (int j = 0; j < 64; j++) {
    if ((keep >> j) & 1ULL) {
      int r = pre + __popcll(keep & ((1ULL << j) - 1ULL));
      if (r < POST_N) {
        int i = lane * 64 + j;
        double4 b = tb[i];
        out[r * 4 + 0] = (float)b.x;
        out[r * 4 + 1] = (float)b.y;
        out[r * 4 + 2] = (float)b.z;
        out[r * 4 + 3] = (float)b.w;
        out[8000 + r] = ts[i];
      }
    }
  }
}

// =====================================================================
extern "C" void kernel_launch(void* const* d_in, const int* in_sizes, int n_in,
                              void* d_out, int out_size, void* d_ws, size_t ws_size,
                              hipStream_t stream) {
  const float* feats  = (const float*)d_in[1];
  const float* w_conv = (const float*)d_in[2];
  const float* b_conv = (const float*)d_in[3];
  const float* w_cls  = (const float*)d_in[4];
  const float* b_cls  = (const float*)d_in[5];
  const float* w_reg  = (const float*)d_in[6];
  const float* b_reg  = (const float*)d_in[7];
  float* out = (float*)d_out;

  char* p = (char*)d_ws;
  auto carve = [&p](size_t bytes) -> void* {
    void* r = (void*)p;
    p += (bytes + 255) & ~(size_t)255;
    return r;
  };
  float*   fpad    = (float*)carve(sizeof(float) * FPAD_FLOATS);       // 17.0 MB
  float*   wt      = (float*)carve(sizeof(float) * 9216 * 512);        // 18.9 MB
  float*   hid     = (float*)carve(sizeof(float) * COUT * HIDP);       //  8.4 MB
  float*   hidp    = (float*)carve(sizeof(float) * KSLICES * COUT * HIDP); // 33.6 MB
  float*   scoresb = (float*)carve(sizeof(float) * 9 * NPOS);
  float*   deltab  = (float*)carve(sizeof(float) * 36 * NPOS);
  double4* boxesd  = (double4*)carve(sizeof(double4) * NA);
  u64*     keys    = (u64*)carve(sizeof(u64) * NA);
  float*   smask   = (float*)carve(sizeof(float) * NA);
  u32*     hist    = (u32*)carve(sizeof(u32) * 65536);
  u32*     ctrl    = (u32*)carve(256);
  u64*     candK   = (u64*)carve(sizeof(u64) * NA);
  u32*     candG   = (u32*)carve(sizeof(u32) * NA);
  double4* tb      = (double4*)carve(sizeof(double4) * TBN);
  float*   ts      = (float*)carve(sizeof(float) * TBN);
  u64*     maskb   = (u64*)carve(sizeof(u64) * (size_t)TBN * MASKW);   //  2.0 MB
  (void)ws_size; (void)in_sizes; (void)n_in; (void)out_size;           // ~83 MB total

  k_pad<<<16642, 256, 0, stream>>>(feats, fpad);
  k_wt<<<dim3(144, 8), 256, 0, stream>>>(w_conv, wt);
  k_init<<<256, 256, 0, stream>>>(hist, ctrl, tb, ts);
  k_conv<<<dim3(16, 16, KSLICES), 256, 0, stream>>>(fpad, wt, hidp);
  k_reduce<<<8192, 256, 0, stream>>>(hidp, b_conv, hid);
  k_head<<<dim3(15, 45), 256, 0, stream>>>(hid, w_cls, b_cls, w_reg, b_reg, scoresb, deltab);
  k_prop<<<134, 256, 0, stream>>>(scoresb, deltab, boxesd, keys, smask, hist, out);
  k_scan<<<1, 256, 0, stream>>>(hist, ctrl);
  k_compact<<<134, 256, 0, stream>>>(keys, ctrl, candK, candG);
  k_rank<<<134, 256, 0, stream>>>(candK, candG, ctrl, boxesd, smask, tb, ts);
  k_mask<<<dim3(MASKW, 16), 256, 0, stream>>>(tb, maskb);
  k_nms<<<1, 64, 0, stream>>>(maskb, ts, tb, out);
}